// Round 2
// baseline (3365.291 us; speedup 1.0000x reference)
//
#include <hip/hip_runtime.h>
#include <math.h>

#define DIMN 20
#define DD 21
#define NN 2048
#define MCN 32
#define UNITS 128
#define SIGC 0.2f
#define MUC 0.05f
#define RC 0.05f
#define DELTAC 0.01f

#define TM 32
#define PTOT (NN + MCN*NN + NN)
#define NBLK (PTOT/TM)

// ws layout (floats)
#define OFF_L 0
#define OFF_WT 512
#define OFF_U4 (OFF_WT + 4*16384)        // 66048 : packed [Uz|Ug|Ur|Uh] 21x512
#define OFF_W3 (OFF_U4 + DD*512)         // 76800 : packed [Wz|Wg|Wr] 128x384
#define OFF_FP1 (OFF_W3 + UNITS*384)     // 125952
#define OFF_VAL1 (OFF_FP1 + NN*DD)
#define OFF_VAL2 (OFF_VAL1 + NN)
#define OFF_T12  (OFF_VAL2 + NN)         // end ~175k floats (~700 KB)

// LDS layout (floats): S0 | S1 | S2 | Db | xT   = 17,056 floats = 68,224 B -> 2 blocks/CU
#define L_S0 0
#define L_S1 4096
#define L_S2 8192
#define L_D  12288
#define L_XT 16384
#define L_TOT (16384 + 672)

#define ELT44(...) _Pragma("unroll") for (int p = 0; p < 4; p++){ _Pragma("unroll") for (int jj = 0; jj < 4; jj++){ __VA_ARGS__; } }

__device__ __forceinline__ int offq(int row, int p0){
    return row*32 + ((p0 + 4*(row&7)) & 31);
}
__device__ __forceinline__ int offs(int row, int p){
    return row*32 + (((p & 28) + 4*(row&7)) & 31) + (p & 3);
}

#define FMA16(acc, s4, w4) \
  acc[0][0]=fmaf(s4.x,w4.x,acc[0][0]); acc[0][1]=fmaf(s4.x,w4.y,acc[0][1]); \
  acc[0][2]=fmaf(s4.x,w4.z,acc[0][2]); acc[0][3]=fmaf(s4.x,w4.w,acc[0][3]); \
  acc[1][0]=fmaf(s4.y,w4.x,acc[1][0]); acc[1][1]=fmaf(s4.y,w4.y,acc[1][1]); \
  acc[1][2]=fmaf(s4.y,w4.z,acc[1][2]); acc[1][3]=fmaf(s4.y,w4.w,acc[1][3]); \
  acc[2][0]=fmaf(s4.z,w4.x,acc[2][0]); acc[2][1]=fmaf(s4.z,w4.y,acc[2][1]); \
  acc[2][2]=fmaf(s4.z,w4.z,acc[2][2]); acc[2][3]=fmaf(s4.z,w4.w,acc[2][3]); \
  acc[3][0]=fmaf(s4.w,w4.x,acc[3][0]); acc[3][1]=fmaf(s4.w,w4.y,acc[3][1]); \
  acc[3][2]=fmaf(s4.w,w4.z,acc[3][2]); acc[3][3]=fmaf(s4.w,w4.w,acc[3][3]);

// acc += vec[k][p] * W[k][j], W read DIRECTLY from global (L1/L2-cached),
// 2-stage register prefetch (load group c+1 before FMA group c). No barriers.
__device__ __forceinline__ void mm_g(const float* __restrict__ gW, int K,
    const float* __restrict__ vec, float acc[4][4], int jg, int p0)
{
    const float* wp = gW + 4*jg;
    int nk = K >> 2;
    float4 wa[4], sa[4];
    if (nk > 0){
        #pragma unroll
        for (int kk = 0; kk < 4; kk++){
            wa[kk] = *(const float4*)(wp + kk*UNITS);
            sa[kk] = *(const float4*)(vec + offq(kk, p0));
        }
    }
    for (int c = 0; c < nk; c++){
        float4 wb[4], sb[4];
        if (c + 1 < nk){
            int kn = (c+1)*4;
            #pragma unroll
            for (int kk = 0; kk < 4; kk++){
                int k = kn + kk;
                wb[kk] = *(const float4*)(wp + k*UNITS);
                sb[kk] = *(const float4*)(vec + k*32 + ((p0 + 4*(k&7)) & 31));
            }
        }
        #pragma unroll
        for (int kk = 0; kk < 4; kk++){ FMA16(acc, sa[kk], wa[kk]) }
        if (c + 1 < nk){
            #pragma unroll
            for (int kk = 0; kk < 4; kk++){ wa[kk] = wb[kk]; sa[kk] = sb[kk]; }
        }
    }
    for (int k = nk*4; k < K; k++){
        float4 w4 = *(const float4*)(wp + k*UNITS);
        float4 s4 = *(const float4*)(vec + offq(k, p0));
        FMA16(acc, s4, w4)
    }
}

// fused z,g,r: W3 rows of 384 ([z|g|r]); one s4 feeds 48 FMAs
__device__ __forceinline__ void mm3_g(const float* __restrict__ gW, int K,
    const float* __restrict__ vec, float a0[4][4], float a1[4][4], float a2[4][4],
    int jg, int p0)
{
    const float* wp = gW + 4*jg;
    int nk = K >> 1;
    float4 wa[2][3], sa[2];
    if (nk > 0){
        #pragma unroll
        for (int kk = 0; kk < 2; kk++){
            const float* r = wp + kk*384;
            wa[kk][0] = *(const float4*)(r);
            wa[kk][1] = *(const float4*)(r + 128);
            wa[kk][2] = *(const float4*)(r + 256);
            sa[kk] = *(const float4*)(vec + offq(kk, p0));
        }
    }
    for (int c = 0; c < nk; c++){
        float4 wb[2][3], sb[2];
        if (c + 1 < nk){
            int kn = (c+1)*2;
            #pragma unroll
            for (int kk = 0; kk < 2; kk++){
                int k = kn + kk;
                const float* r = wp + k*384;
                wb[kk][0] = *(const float4*)(r);
                wb[kk][1] = *(const float4*)(r + 128);
                wb[kk][2] = *(const float4*)(r + 256);
                sb[kk] = *(const float4*)(vec + k*32 + ((p0 + 4*(k&7)) & 31));
            }
        }
        #pragma unroll
        for (int kk = 0; kk < 2; kk++){
            FMA16(a0, sa[kk], wa[kk][0])
            FMA16(a1, sa[kk], wa[kk][1])
            FMA16(a2, sa[kk], wa[kk][2])
        }
        if (c + 1 < nk){
            #pragma unroll
            for (int kk = 0; kk < 2; kk++){
                wa[kk][0]=wb[kk][0]; wa[kk][1]=wb[kk][1]; wa[kk][2]=wb[kk][2]; sa[kk]=sb[kk];
            }
        }
    }
    for (int k = nk*2; k < K; k++){
        const float* r = wp + k*384;
        float4 s4 = *(const float4*)(vec + offq(k, p0));
        float4 w0 = *(const float4*)(r);
        float4 w1x = *(const float4*)(r + 128);
        float4 w2 = *(const float4*)(r + 256);
        FMA16(a0, s4, w0) FMA16(a1, s4, w1x) FMA16(a2, s4, w2)
    }
}

// fused U-pass for all 4 gates: U4 rows of 512 ([z|g|r|h]); one s4 feeds 64 FMAs
__device__ __forceinline__ void mm4_g(const float* __restrict__ gW, int K,
    const float* __restrict__ vec, float a0[4][4], float a1[4][4], float a2[4][4], float a3[4][4],
    int jg, int p0)
{
    const float* wp = gW + 4*jg;
    int nk = K >> 1;
    float4 wa[2][4], sa[2];
    if (nk > 0){
        #pragma unroll
        for (int kk = 0; kk < 2; kk++){
            const float* r = wp + kk*512;
            wa[kk][0] = *(const float4*)(r);
            wa[kk][1] = *(const float4*)(r + 128);
            wa[kk][2] = *(const float4*)(r + 256);
            wa[kk][3] = *(const float4*)(r + 384);
            sa[kk] = *(const float4*)(vec + offq(kk, p0));
        }
    }
    for (int c = 0; c < nk; c++){
        float4 wb[2][4], sb[2];
        if (c + 1 < nk){
            int kn = (c+1)*2;
            #pragma unroll
            for (int kk = 0; kk < 2; kk++){
                int k = kn + kk;
                const float* r = wp + k*512;
                wb[kk][0] = *(const float4*)(r);
                wb[kk][1] = *(const float4*)(r + 128);
                wb[kk][2] = *(const float4*)(r + 256);
                wb[kk][3] = *(const float4*)(r + 384);
                sb[kk] = *(const float4*)(vec + k*32 + ((p0 + 4*(k&7)) & 31));
            }
        }
        #pragma unroll
        for (int kk = 0; kk < 2; kk++){
            FMA16(a0, sa[kk], wa[kk][0])
            FMA16(a1, sa[kk], wa[kk][1])
            FMA16(a2, sa[kk], wa[kk][2])
            FMA16(a3, sa[kk], wa[kk][3])
        }
        if (c + 1 < nk){
            #pragma unroll
            for (int kk = 0; kk < 2; kk++){
                wa[kk][0]=wb[kk][0]; wa[kk][1]=wb[kk][1]; wa[kk][2]=wb[kk][2]; wa[kk][3]=wb[kk][3];
                sa[kk]=sb[kk];
            }
        }
    }
    for (int k = nk*2; k < K; k++){
        const float* r = wp + k*512;
        float4 s4 = *(const float4*)(vec + offq(k, p0));
        float4 w0 = *(const float4*)(r);
        float4 w1x = *(const float4*)(r + 128);
        float4 w2 = *(const float4*)(r + 256);
        float4 w3 = *(const float4*)(r + 384);
        FMA16(a0, s4, w0) FMA16(a1, s4, w1x) FMA16(a2, s4, w2) FMA16(a3, s4, w3)
    }
}

__device__ __forceinline__ void write_own(float* buf, const float v[4][4], int j0, int p0){
    #pragma unroll
    for (int jj = 0; jj < 4; jj++){
        int j = j0 + jj;
        float4 q = make_float4(v[0][jj], v[1][jj], v[2][jj], v[3][jj]);
        *(float4*)(buf + offq(j, p0)) = q;
    }
}
__device__ __forceinline__ void read_own(const float* buf, float v[4][4], int j0, int p0){
    #pragma unroll
    for (int jj = 0; jj < 4; jj++){
        int j = j0 + jj;
        float4 q = *(const float4*)(buf + offq(j, p0));
        v[0][jj]=q.x; v[1][jj]=q.y; v[2][jj]=q.z; v[3][jj]=q.w;
    }
}

__global__ void chol_kernel(float* __restrict__ Lout)
{
    if (threadIdx.x == 0 && blockIdx.x == 0) {
        double Lc[DIMN][DIMN];
        for (int i = 0; i < DIMN; i++)
            for (int j = 0; j <= i; j++) {
                double s = 0.01 * (0.5 + (i == j ? 0.5 : 0.0));
                for (int t2 = 0; t2 < j; t2++) s -= Lc[i][t2] * Lc[j][t2];
                Lc[i][j] = (i == j) ? sqrt(s) : s / Lc[j][j];
            }
        for (int i = 0; i < DIMN; i++)
            for (int j = 0; j < DIMN; j++)
                Lout[i*DIMN + j] = (j <= i) ? (float)Lc[i][j] : 0.0f;
    }
}

__global__ void transpose_k(const float* __restrict__ wz, const float* __restrict__ wg,
                            const float* __restrict__ wr, const float* __restrict__ wh,
                            float* __restrict__ WT)
{
    int idx = blockIdx.x*256 + threadIdx.x;           // 0..65535
    int q = idx >> 14, r2 = idx & 16383, k = r2 >> 7, j = r2 & 127;
    const float* src = (q==0)? wz : (q==1)? wg : (q==2)? wr : wh;
    WT[(q<<14) + j*UNITS + k] = src[k*UNITS + j];
}

// pack U4 = [uz|ug|ur|uh] 21x512 and W3 = [wz|wg|wr] 128x384
__global__ void pack_u4w3(const float* __restrict__ uz, const float* __restrict__ ug,
                          const float* __restrict__ ur, const float* __restrict__ uh,
                          const float* __restrict__ wz, const float* __restrict__ wg,
                          const float* __restrict__ wr,
                          float* __restrict__ U4, float* __restrict__ W3)
{
    int idx = blockIdx.x*256 + threadIdx.x;
    if (idx < 128*384){
        int k = idx/384, c = idx - k*384, g = c >> 7, j = c & 127;
        const float* s = (g==0)? wz : (g==1)? wg : wr;
        W3[idx] = s[k*UNITS + j];
        return;
    }
    int i2 = idx - 128*384;
    if (i2 < 21*512){
        int k = i2/512, c = i2 - k*512, g = c >> 7, j = c & 127;
        const float* s = (g==0)? uz : (g==1)? ug : (g==2)? ur : uh;
        U4[i2] = s[k*UNITS + j];
    }
}

__global__ __launch_bounds__(256, 2) void dgm_main(
    const float* __restrict__ inputs, const float* __restrict__ eps,
    const float* __restrict__ w1, const float* __restrict__ b1,
    const float* __restrict__ uz, const float* __restrict__ bz,
    const float* __restrict__ ug, const float* __restrict__ bg,
    const float* __restrict__ ur, const float* __restrict__ br,
    const float* __restrict__ uh, const float* __restrict__ wh, const float* __restrict__ bh,
    const float* __restrict__ wv, const float* __restrict__ bv,
    const float* __restrict__ Lm, const float* __restrict__ WT,
    const float* __restrict__ U4, const float* __restrict__ W3,
    float* __restrict__ fp1, float* __restrict__ val1, float* __restrict__ val2,
    float* __restrict__ t12acc)
{
    __shared__ float lds[L_TOT];
    float* S0 = lds + L_S0;
    float* S1 = lds + L_S1;
    float* S2 = lds + L_S2;
    float* Db = lds + L_D;
    float* xT = lds + L_XT;

    const int t  = threadIdx.x;
    const int jg = t & 31;
    const int pg = t >> 5;
    const int p0 = pg * 4;
    const int j0 = jg * 4;
    const int P0 = blockIdx.x * TM;
    const int type = (P0 < NN) ? 0 : (P0 < NN + MCN*NN) ? 1 : 2;
    int base_n = 0, mrow = 0;
    if (type == 1){ int q = P0 - NN; mrow = q >> 11; base_n = q & (NN-1); }

    // ---- build x tile ----
    {
        int p = t & 31, kq = t >> 5;
        for (int ki = 0; ki < 3; ki++){
            int k = kq + 8*ki;
            if (k > DIMN) break;
            float xv;
            if (type == 0){
                xv = inputs[(P0 + p)*DD + k];
            } else if (type == 2){
                xv = inputs[(NN + (P0 - NN - MCN*NN) + p)*DD + k];
            } else {
                int n = base_n + p;
                float x1v = inputs[n*DD + k];
                if (k == DIMN) xv = x1v;
                else {
                    const float* ep = eps + (size_t)(mrow*NN + n)*DIMN;
                    float a = x1v;
                    for (int d = 0; d < DIMN; d++) a = fmaf(ep[d], Lm[k*DIMN + d], a);
                    xv = x1v + a * (SIGC * x1v);
                }
            }
            xT[offs(k, p)] = xv;
        }
    }
    __syncthreads();

    // ---- forward ----
    float s_own[4][4];
    {
        float acc[4][4];
        float4 b = *(const float4*)(b1 + j0);
        #pragma unroll
        for (int p = 0; p < 4; p++){ acc[p][0]=b.x; acc[p][1]=b.y; acc[p][2]=b.z; acc[p][3]=b.w; }
        mm_g(w1, DD, xT, acc, jg, p0);
        ELT44(s_own[p][jj] = tanhf(acc[p][jj]))
        write_own(S0, s_own, j0, p0);
        __syncthreads();
    }

    float zt[4][4], gt[4][4], rt[4][4], ht[4][4];

// computes zt,gt,rt,ht for input state SIN; SMUL is the state multiplying r (s*r)
#define GATES(SIN, SMUL) \
    { \
    float4 q0 = *(const float4*)(bz + j0), q1 = *(const float4*)(bg + j0); \
    float4 q2 = *(const float4*)(br + j0), q3 = *(const float4*)(bh + j0); \
    float az[4][4], ag[4][4], ar[4][4], ah[4][4]; \
    _Pragma("unroll") for (int p = 0; p < 4; p++){ \
        az[p][0]=q0.x; az[p][1]=q0.y; az[p][2]=q0.z; az[p][3]=q0.w; \
        ag[p][0]=q1.x; ag[p][1]=q1.y; ag[p][2]=q1.z; ag[p][3]=q1.w; \
        ar[p][0]=q2.x; ar[p][1]=q2.y; ar[p][2]=q2.z; ar[p][3]=q2.w; \
        ah[p][0]=q3.x; ah[p][1]=q3.y; ah[p][2]=q3.z; ah[p][3]=q3.w; } \
    mm4_g(U4, DD, xT, az, ag, ar, ah, jg, p0); \
    mm3_g(W3, UNITS, SIN, az, ag, ar, jg, p0); \
    ELT44(zt[p][jj]=tanhf(az[p][jj]); gt[p][jj]=tanhf(ag[p][jj]); rt[p][jj]=tanhf(ar[p][jj])) \
    { float tt[4][4]; ELT44(tt[p][jj] = SMUL[p][jj]*rt[p][jj]) \
      __syncthreads(); write_own(Db, tt, j0, p0); __syncthreads(); } \
    mm_g(wh, UNITS, Db, ah, jg, p0); \
    ELT44(ht[p][jj] = tanhf(ah[p][jj])) \
    }

#define FWD_LAYER(SIN) \
    GATES(SIN, s_own) \
    ELT44(s_own[p][jj] = (1.f - gt[p][jj])*ht[p][jj] + zt[p][jj]*s_own[p][jj])

    FWD_LAYER(S0)
    write_own(S1, s_own, j0, p0);
    __syncthreads();
    FWD_LAYER(S1)
    write_own(S2, s_own, j0, p0);
    __syncthreads();
    FWD_LAYER(S2)          // zt/gt/rt/ht stay live in registers for bwd layer 3

    // ---- value head ----
    {
        float4 wv4 = *(const float4*)(wv + j0);
        float vs[4];
        #pragma unroll
        for (int p = 0; p < 4; p++)
            vs[p] = s_own[p][0]*wv4.x + s_own[p][1]*wv4.y + s_own[p][2]*wv4.z + s_own[p][3]*wv4.w;
        __syncthreads();   // layer-3 mm_g(wh) readers of Db done
        *(float4*)(Db + jg*32 + p0) = make_float4(vs[0], vs[1], vs[2], vs[3]);
        __syncthreads();
        if (t < TM){
            float v = bv[0];
            for (int j2 = 0; j2 < 32; j2++) v += Db[j2*32 + t];
            if (type == 0) val1[P0 + t] = v;
            else if (type == 2) val2[P0 + t - NN - MCN*NN] = v;
        }
        __syncthreads();
    }
    if (type == 2) return;

    // ---- backward ----
    float ds[4][4];
    {
        float4 wv4 = *(const float4*)(wv + j0);
        #pragma unroll
        for (int p = 0; p < 4; p++){ ds[p][0]=wv4.x; ds[p][1]=wv4.y; ds[p][2]=wv4.z; ds[p][3]=wv4.w; }
    }
    float dga_z[4][4], dga_g[4][4], dga_r[4][4], dga_h[4][4], v0[4][4];
    ELT44(dga_z[p][jj]=0.f; dga_g[p][jj]=0.f; dga_r[p][jj]=0.f; dga_h[p][jj]=0.f)

    const float* WTz = WT;
    const float* WTg = WT + 16384;
    const float* WTr = WT + 2*16384;
    const float* WTh = WT + 3*16384;

// MODE 0: gates already live in zt/gt/rt/ht; MODE 1: recompute from SINP
#define BWD_LAYER(SLP, SINP, MODE) \
    { \
    float sl[4][4]; \
    read_own(SLP, sl, j0, p0); \
    if (MODE){ GATES(SINP, sl) } \
    float dhp[4][4]; float dzp[4][4]; float dgp[4][4]; float dsn[4][4]; \
    ELT44(float d=ds[p][jj]; float g=gt[p][jj]; float h=ht[p][jj]; float z=zt[p][jj]; float s=sl[p][jj]; \
        dhp[p][jj] = d*(1.f - g)*(1.f - h*h); \
        dgp[p][jj] = -d*h*(1.f - g*g); \
        dzp[p][jj] = d*s*(1.f - z*z); \
        dsn[p][jj] = d*z; \
        dga_h[p][jj] += dhp[p][jj]; \
        dga_g[p][jj] += dgp[p][jj]; \
        dga_z[p][jj] += dzp[p][jj]) \
    __syncthreads(); write_own(Db, dhp, j0, p0); __syncthreads(); \
    float dsr[4][4]; \
    ELT44(dsr[p][jj] = 0.f) \
    mm_g(WTh, UNITS, Db, dsr, jg, p0); \
    float drp[4][4]; \
    ELT44(float dr=dsr[p][jj]; float r=rt[p][jj]; float s=sl[p][jj]; \
        drp[p][jj] = dr*s*(1.f - r*r); \
        dga_r[p][jj] += drp[p][jj]; \
        dsn[p][jj] += dr*r) \
    __syncthreads(); write_own(Db, dzp, j0, p0); __syncthreads(); \
    mm_g(WTz, UNITS, Db, dsn, jg, p0); \
    __syncthreads(); write_own(Db, dgp, j0, p0); __syncthreads(); \
    mm_g(WTg, UNITS, Db, dsn, jg, p0); \
    __syncthreads(); write_own(Db, drp, j0, p0); __syncthreads(); \
    mm_g(WTr, UNITS, Db, dsn, jg, p0); \
    ELT44(ds[p][jj] = dsn[p][jj]) \
    }

    BWD_LAYER(S2, S2, 0)   // gates live from FWD_LAYER(S2)
    BWD_LAYER(S1, S1, 1)
    BWD_LAYER(S0, S0, 1)

    // first layer backward
    {
        float s0l[4][4];
        read_own(S0, s0l, j0, p0);
        ELT44(v0[p][jj] = ds[p][jj]*(1.f - s0l[p][jj]*s0l[p][jj]))
    }

    if (type == 1){
        // rebuild violation V into Db rows 0..19 (k-major, swizzled)
        __syncthreads();   // mm_g(WTr) readers of Db done
        {
            int p = t & 31, kq = t >> 5;
            for (int ki = 0; ki < 3; ki++){
                int k = kq + 8*ki;
                if (k >= DIMN) break;
                int n = base_n + p;
                float x1v = inputs[n*DD + k];
                const float* ep = eps + (size_t)(mrow*NN + n)*DIMN;
                float a = x1v;
                for (int d = 0; d < DIMN; d++) a = fmaf(ep[d], Lm[k*DIMN + d], a);
                Db[offs(k, p)] = a * (SIGC * x1v);
            }
        }
        __syncthreads();
        float proj[4] = {0.f, 0.f, 0.f, 0.f};

#define PROJ_PASS(UMAT, SEL) \
        { float uv[4][4]; \
          ELT44(uv[p][jj] = 0.f) \
          mm_g(UMAT, DIMN, Db, uv, jg, p0); \
          ELT44(proj[p] += uv[p][jj]*SEL[p][jj]) }

        PROJ_PASS(uz, dga_z)
        PROJ_PASS(ug, dga_g)
        PROJ_PASS(ur, dga_r)
        PROJ_PASS(uh, dga_h)
        PROJ_PASS(w1, v0)

        // reduce over jg: scratch rows 24..55 of Db (disjoint from V rows 0..19)
        *(float4*)(Db + (24 + jg)*32 + p0) = make_float4(proj[0], proj[1], proj[2], proj[3]);
        __syncthreads();
        if (t < TM){
            float s = 0.f;
            for (int j2 = 0; j2 < 32; j2++) s += Db[(24 + j2)*32 + t];
            atomicAdd(t12acc + base_n + t, s);
        }
    } else {
        // type 0: full fprime
        float dxp[3] = {0.f, 0.f, 0.f};
        int pi = t >> 3, il = t & 7;

#define DX_PASS(UMAT, SEL) \
        __syncthreads(); \
        write_own(Db, SEL, j0, p0); \
        __syncthreads(); \
        _Pragma("unroll") for (int ii = 0; ii < 3; ii++){ \
            int i = il + 8*ii; \
            if (i < DD){ \
                const float* Urow = UMAT + i*UNITS; \
                float a = 0.f; \
                for (int j2 = 0; j2 < UNITS; j2++) a = fmaf(Db[offs(j2, pi)], Urow[j2], a); \
                dxp[ii] += a; \
            } \
        }

        DX_PASS(uz, dga_z)
        DX_PASS(ug, dga_g)
        DX_PASS(ur, dga_r)
        DX_PASS(uh, dga_h)
        DX_PASS(w1, v0)

        #pragma unroll
        for (int ii = 0; ii < 3; ii++){
            int i = il + 8*ii;
            if (i < DD) fp1[(P0 + pi)*DD + i] = dxp[ii];
        }
    }
}

__global__ void finalize_k(const float* __restrict__ inputs, const float* __restrict__ eps,
    const float* __restrict__ Lm, const float* __restrict__ fp1, const float* __restrict__ val1,
    const float* __restrict__ val2, const float* __restrict__ t12acc, float* __restrict__ out)
{
    int n = blockIdx.x*256 + threadIdx.x;
    if (n >= NN) return;
    float fp[DD];
    #pragma unroll
    for (int k = 0; k < DD; k++) fp[k] = fp1[n*DD + k];
    float t11 = fp[DIMN];
    #pragma unroll
    for (int k = 0; k < DIMN; k++) t11 = fmaf(MUC*inputs[n*DD + k], fp[k], t11);
    float esum[DIMN];
    #pragma unroll
    for (int d = 0; d < DIMN; d++){
        float a = 0.f;
        for (int m = 0; m < MCN; m++) a += eps[(size_t)(m*NN + n)*DIMN + d];
        esum[d] = a;
    }
    float t12b = 0.f;
    #pragma unroll
    for (int k = 0; k < DIMN; k++){
        float loc = inputs[n*DD + k];
        float ssum = (float)MCN * loc;
        #pragma unroll
        for (int d = 0; d < DIMN; d++) ssum = fmaf(esum[d], Lm[k*DIMN + d], ssum);
        float vsum = ssum * (SIGC*loc);
        t12b = fmaf(fp[k], vsum, t12b);
    }
    float term12 = (t12acc[n] - t12b) * (1.0f/(DELTAC*(float)MCN));
    out[n] = t11 + 0.5f*term12 - RC*val1[n];

    float prod = 1.f;
    #pragma unroll
    for (int k = 0; k < DIMN; k++) prod *= inputs[(NN + n)*DD + k];
    float payoff = powf(prod, 1.0f/(float)DIMN);
    if (!(payoff > 0.f)) payoff = 0.f;
    out[NN + n] = val2[n] - payoff;
}

extern "C" void kernel_launch(void* const* d_in, const int* in_sizes, int n_in,
                              void* d_out, int out_size, void* d_ws, size_t ws_size,
                              hipStream_t stream)
{
    const float* inputs = (const float*)d_in[0];
    const float* eps    = (const float*)d_in[1];
    const float* w1     = (const float*)d_in[2];
    const float* b1     = (const float*)d_in[3];
    const float* uz     = (const float*)d_in[4];
    const float* wz     = (const float*)d_in[5];
    const float* bz     = (const float*)d_in[6];
    const float* ug     = (const float*)d_in[7];
    const float* wg     = (const float*)d_in[8];
    const float* bg     = (const float*)d_in[9];
    const float* urr    = (const float*)d_in[10];
    const float* wr     = (const float*)d_in[11];
    const float* br     = (const float*)d_in[12];
    const float* uh     = (const float*)d_in[13];
    const float* wh     = (const float*)d_in[14];
    const float* bh     = (const float*)d_in[15];
    const float* wv     = (const float*)d_in[16];
    const float* bv     = (const float*)d_in[17];

    float* ws    = (float*)d_ws;
    float* Lm    = ws + OFF_L;
    float* WT    = ws + OFF_WT;
    float* U4    = ws + OFF_U4;
    float* W3    = ws + OFF_W3;
    float* fp1   = ws + OFF_FP1;
    float* val1  = ws + OFF_VAL1;
    float* val2  = ws + OFF_VAL2;
    float* t12   = ws + OFF_T12;
    float* out   = (float*)d_out;

    hipMemsetAsync(t12, 0, NN*sizeof(float), stream);
    hipLaunchKernelGGL(chol_kernel, dim3(1), dim3(64), 0, stream, Lm);
    hipLaunchKernelGGL(transpose_k, dim3(256), dim3(256), 0, stream, wz, wg, wr, wh, WT);
    hipLaunchKernelGGL(pack_u4w3, dim3(234), dim3(256), 0, stream, uz, ug, urr, uh, wz, wg, wr, U4, W3);
    hipLaunchKernelGGL(dgm_main, dim3(NBLK), dim3(256), 0, stream,
        inputs, eps, w1, b1, uz, bz, ug, bg, urr, br, uh, wh, bh, wv, bv,
        Lm, WT, U4, W3, fp1, val1, val2, t12);
    hipLaunchKernelGGL(finalize_k, dim3(8), dim3(256), 0, stream,
        inputs, eps, Lm, fp1, val1, val2, t12, out);
}